// Round 3
// baseline (164.930 us; speedup 1.0000x reference)
//
#include <hip/hip_runtime.h>
#include <math.h>

namespace {
constexpr int kB = 256;
constexpr int kN = 1024;
constexpr int kC = 512;
constexpr int kNP1 = kN + 1;  // 1025 (visual rows + dustbin)
constexpr float kEPS = 1e-6f;
constexpr float kPOW = 0.9523809523809523f;   // ALPHA/(ALPHA+REG) = 1/1.05
constexpr float kSCALE = 28.8539008177792681f; // 20 * log2(e)

// fast path ws: vis8 only (sim lives in LDS now)
constexpr size_t kVis8Bytes = (size_t)kB * kN * kC;  // 134,217,728

// ---- fallback ws layout (floats), round-1 fp32 path ----
constexpr size_t kFbSimOff = 0;
constexpr size_t kFbGammaOff = (size_t)kB * kNP1;
constexpr size_t kFbPartialOff = kFbGammaOff + (size_t)kB * kN;
constexpr int kNSplit = 4;
constexpr int kRowsPerSplit = kN / kNSplit;  // 256

typedef float f32x2 __attribute__((ext_vector_type(2)));
typedef float f32x4 __attribute__((ext_vector_type(4)));
}  // namespace

// ===========================================================================
// FUSED FAST PATH: one block per batch, 1024 threads (16 waves).
// Phase A: sims -> LDS, fp8 copy -> ws (vis fp32 reads are nontemporal).
// Phase B: Sinkhorn in LDS, einsum reading vis8 (LLC-resident), outputs.
// ===========================================================================
__global__ __launch_bounds__(1024) void fused_kernel(
    const float* __restrict__ prompt,       // [B, C]
    const float* __restrict__ vis,          // [B, N, C]
    const float* __restrict__ dustbin,      // [C]
    unsigned char* __restrict__ vis8,       // [B, N, C] e4m3 scratch
    float* __restrict__ p_obs,              // [B, C]
    float* __restrict__ mass_out) {         // [B]
  const int b = blockIdx.x;
  const int t = threadIdx.x;
  const int w = t >> 6;       // wave 0..15
  const int lane = t & 63;

  __shared__ float sims[kNP1];            // later reused as gamma
  __shared__ float red[16];
  __shared__ float pacc[16][64][8];       // 32 KB einsum partials

  // prompt fragment: lane owns channels [lane*8, lane*8+8), kept in regs
  const float* prow = prompt + (size_t)b * kC;
  const int coff = lane * 8;
  const f32x4 pa = *reinterpret_cast<const f32x4*>(prow + coff);
  const f32x4 pb = *reinterpret_cast<const f32x4*>(prow + coff + 4);
  float psq = pa.x * pa.x + pa.y * pa.y + pa.z * pa.z + pa.w * pa.w +
              pb.x * pb.x + pb.y * pb.y + pb.z * pb.z + pb.w * pb.w;
#pragma unroll
  for (int s = 1; s < 64; s <<= 1) psq += __shfl_xor(psq, s);
  const float pn = fmaxf(sqrtf(psq), 1e-12f);

  // -------- Phase A: 64 rows per wave --------
  const size_t rowbase = (size_t)b * kN + (size_t)w * 64;
  const float* vptr = vis + rowbase * kC;
  unsigned char* v8ptr = vis8 + rowbase * kC;
#pragma unroll 2
  for (int r = 0; r < 64; ++r) {
    const float* vrow = vptr + (size_t)r * kC;
    const f32x4 va = __builtin_nontemporal_load(
        reinterpret_cast<const f32x4*>(vrow + coff));
    const f32x4 vb = __builtin_nontemporal_load(
        reinterpret_cast<const f32x4*>(vrow + coff + 4));

    float dot = va.x * pa.x + va.y * pa.y + va.z * pa.z + va.w * pa.w +
                vb.x * pb.x + vb.y * pb.y + vb.z * pb.z + vb.w * pb.w;
    float vsq = va.x * va.x + va.y * va.y + va.z * va.z + va.w * va.w +
                vb.x * vb.x + vb.y * vb.y + vb.z * vb.z + vb.w * vb.w;

    int pk0 = __builtin_amdgcn_cvt_pk_fp8_f32(va.x, va.y, 0, false);
    pk0 = __builtin_amdgcn_cvt_pk_fp8_f32(va.z, va.w, pk0, true);
    int pk1 = __builtin_amdgcn_cvt_pk_fp8_f32(vb.x, vb.y, 0, false);
    pk1 = __builtin_amdgcn_cvt_pk_fp8_f32(vb.z, vb.w, pk1, true);
    uint2 wv;
    wv.x = (unsigned)pk0;
    wv.y = (unsigned)pk1;
    *reinterpret_cast<uint2*>(v8ptr + (size_t)r * kC + coff) = wv;

#pragma unroll
    for (int s = 1; s < 64; s <<= 1) {
      dot += __shfl_xor(dot, s);
      vsq += __shfl_xor(vsq, s);
    }
    if (lane == 0)
      sims[w * 64 + r] = dot / (pn * fmaxf(sqrtf(vsq), 1e-12f));
  }

  // dustbin sim by wave 0 (dustbin is tiny / cache-hot)
  if (w == 0) {
    const f32x4 da = *reinterpret_cast<const f32x4*>(dustbin + coff);
    const f32x4 db = *reinterpret_cast<const f32x4*>(dustbin + coff + 4);
    float dot = da.x * pa.x + da.y * pa.y + da.z * pa.z + da.w * pa.w +
                db.x * pb.x + db.y * pb.y + db.z * pb.z + db.w * pb.w;
    float vsq = da.x * da.x + da.y * da.y + da.z * da.z + da.w * da.w +
                db.x * db.x + db.y * db.y + db.z * db.z + db.w * db.w;
#pragma unroll
    for (int s = 1; s < 64; s <<= 1) {
      dot += __shfl_xor(dot, s);
      vsq += __shfl_xor(vsq, s);
    }
    if (lane == 0) sims[kN] = dot / (pn * fmaxf(sqrtf(vsq), 1e-12f));
  }
  __syncthreads();

  // -------- Phase B: Sinkhorn (thread t owns n=t; t==0 also dustbin) ------
  const float K0 = exp2f((sims[t] - 1.0f) * kSCALE);
  const float Kd = (t == 0) ? exp2f((sims[kN] - 1.0f) * kSCALE) : 0.0f;
  float v0 = 1.0f, vd = 1.0f, u = 1.0f;
#pragma unroll
  for (int it = 0; it < 3; ++it) {
    float partial = K0 * v0 + Kd * vd;
#pragma unroll
    for (int s = 1; s < 64; s <<= 1) partial += __shfl_xor(partial, s);
    if (lane == 0) red[w] = partial;
    __syncthreads();
    float Kv = 0.f;
#pragma unroll
    for (int w2 = 0; w2 < 16; ++w2) Kv += red[w2];
    __syncthreads();
    u = exp2f(-kPOW * log2f(Kv + kEPS));
    v0 = exp2f(-kPOW * log2f(u * K0 + kEPS));
    vd = exp2f(-kPOW * log2f(u * Kd + kEPS));
  }

  const float g = u * K0 * v0;  // gamma for n = t (< N always)
  sims[t] = g;                  // reuse LDS as gamma (all sims reads done)

  float pm = g;
#pragma unroll
  for (int s = 1; s < 64; s <<= 1) pm += __shfl_xor(pm, s);
  if (lane == 0) red[w] = pm;
  __syncthreads();              // publishes gamma + red
  if (t == 0) {
    float m = 0.f;
#pragma unroll
    for (int w2 = 0; w2 < 16; ++w2) m += red[w2];
    mass_out[b] = m;
  }

  // -------- Phase B: einsum  p_obs[c] = sum_n gamma[n] * vis8[b,n,c] ------
  // wave w handles n = w + 16k; lane owns channels [lane*8, lane*8+8)
  float acc[8] = {0.f, 0.f, 0.f, 0.f, 0.f, 0.f, 0.f, 0.f};
  const unsigned char* v8 = vis8 + (size_t)b * kN * kC + (size_t)coff;
#pragma unroll 8
  for (int k = 0; k < 64; ++k) {
    const int n = w + (k << 4);
    const float gn = sims[n];
    const uint2 wd = *reinterpret_cast<const uint2*>(v8 + (size_t)n * kC);
    const f32x2 f01 = __builtin_amdgcn_cvt_pk_f32_fp8(wd.x, false);
    const f32x2 f23 = __builtin_amdgcn_cvt_pk_f32_fp8(wd.x, true);
    const f32x2 f45 = __builtin_amdgcn_cvt_pk_f32_fp8(wd.y, false);
    const f32x2 f67 = __builtin_amdgcn_cvt_pk_f32_fp8(wd.y, true);
    acc[0] += gn * f01.x; acc[1] += gn * f01.y;
    acc[2] += gn * f23.x; acc[3] += gn * f23.y;
    acc[4] += gn * f45.x; acc[5] += gn * f45.y;
    acc[6] += gn * f67.x; acc[7] += gn * f67.y;
  }
#pragma unroll
  for (int j = 0; j < 8; ++j) pacc[w][lane][j] = acc[j];
  __syncthreads();
  if (t < 512) {
    float s = 0.f;
#pragma unroll
    for (int ss = 0; ss < 16; ++ss) s += pacc[ss][t >> 3][t & 7];
    p_obs[(size_t)b * kC + t] = s;
  }
}

// ===========================================================================
// FALLBACK (fp32 two-pass, round-1 proven; used only if ws < 134.2 MB)
// ===========================================================================
__global__ __launch_bounds__(256) void sim_kernel(
    const float* __restrict__ prompt, const float* __restrict__ vis,
    const float* __restrict__ dustbin, float* __restrict__ sim) {
  const int wid = threadIdx.x >> 6;
  const int lane = threadIdx.x & 63;
  const long long row = (long long)blockIdx.x * 4 + wid;
  if (row >= (long long)kB * kNP1) return;
  const int b = (int)(row / kNP1);
  const int n = (int)(row % kNP1);
  const float* vrow = (n < kN) ? (vis + ((size_t)b * kN + n) * kC) : dustbin;
  const float* prow = prompt + (size_t)b * kC;
  float dot = 0.f, vsq = 0.f, psq = 0.f;
#pragma unroll
  for (int h = 0; h < 2; ++h) {
    const int off = h * 256 + lane * 4;
    const float4 v4 = *reinterpret_cast<const float4*>(vrow + off);
    const float4 p4 = *reinterpret_cast<const float4*>(prow + off);
    dot += v4.x * p4.x + v4.y * p4.y + v4.z * p4.z + v4.w * p4.w;
    vsq += v4.x * v4.x + v4.y * v4.y + v4.z * v4.z + v4.w * v4.w;
    psq += p4.x * p4.x + p4.y * p4.y + p4.z * p4.z + p4.w * p4.w;
  }
#pragma unroll
  for (int s = 1; s < 64; s <<= 1) {
    dot += __shfl_xor(dot, s);
    vsq += __shfl_xor(vsq, s);
    psq += __shfl_xor(psq, s);
  }
  if (lane == 0) {
    const float pn = fmaxf(sqrtf(psq), 1e-12f);
    const float vn = fmaxf(sqrtf(vsq), 1e-12f);
    sim[row] = dot / (pn * vn);
  }
}

__global__ __launch_bounds__(1024) void sinkhorn_kernel(
    const float* __restrict__ sim, float* __restrict__ gamma,
    float* __restrict__ mass_out) {
  const int b = blockIdx.x;
  const int t = threadIdx.x;
  __shared__ float red[16];
  const float* simb = sim + (size_t)b * kNP1;
  const float K0 = exp2f((simb[t] - 1.0f) * kSCALE);
  const float K1 = (t == 0) ? exp2f((simb[kN] - 1.0f) * kSCALE) : 0.0f;
  float v0 = 1.0f, v1 = 1.0f, u = 1.0f;
  for (int it = 0; it < 3; ++it) {
    float partial = K0 * v0 + K1 * v1;
#pragma unroll
    for (int s = 1; s < 64; s <<= 1) partial += __shfl_xor(partial, s);
    if ((t & 63) == 0) red[t >> 6] = partial;
    __syncthreads();
    float Kv = 0.f;
#pragma unroll
    for (int w = 0; w < 16; ++w) Kv += red[w];
    __syncthreads();
    u = exp2f(-kPOW * log2f(Kv + kEPS));
    v0 = exp2f(-kPOW * log2f(u * K0 + kEPS));
    v1 = exp2f(-kPOW * log2f(u * K1 + kEPS));
  }
  const float g0 = u * K0 * v0;
  gamma[(size_t)b * kN + t] = g0;
  float partial = g0;
#pragma unroll
  for (int s = 1; s < 64; s <<= 1) partial += __shfl_xor(partial, s);
  if ((t & 63) == 0) red[t >> 6] = partial;
  __syncthreads();
  if (t == 0) {
    float m = 0.f;
#pragma unroll
    for (int w = 0; w < 16; ++w) m += red[w];
    mass_out[b] = m;
  }
}

__global__ __launch_bounds__(512) void pobs_kernel(
    const float* __restrict__ vis, const float* __restrict__ gamma,
    float* __restrict__ partial) {
  const int b = blockIdx.x / kNSplit;
  const int s = blockIdx.x % kNSplit;
  const int c = threadIdx.x;
  __shared__ float gsm[kRowsPerSplit];
  const float* g = gamma + (size_t)b * kN + (size_t)s * kRowsPerSplit;
  for (int i = threadIdx.x; i < kRowsPerSplit; i += 512) gsm[i] = g[i];
  __syncthreads();
  const float* vbase = vis + ((size_t)b * kN + (size_t)s * kRowsPerSplit) * kC;
  float acc = 0.f;
#pragma unroll 8
  for (int n = 0; n < kRowsPerSplit; ++n)
    acc += gsm[n] * vbase[(size_t)n * kC + c];
  partial[(size_t)blockIdx.x * kC + c] = acc;
}

__global__ __launch_bounds__(256) void reduce_kernel(
    const float* __restrict__ partial, float* __restrict__ p_obs) {
  const int i = blockIdx.x * 256 + threadIdx.x;
  if (i >= kB * kC) return;
  const int b = i / kC;
  const int c = i % kC;
  float s = 0.f;
#pragma unroll
  for (int k = 0; k < kNSplit; ++k)
    s += partial[((size_t)(b * kNSplit + k)) * kC + c];
  p_obs[i] = s;
}

// ===========================================================================

extern "C" void kernel_launch(void* const* d_in, const int* in_sizes, int n_in,
                              void* d_out, int out_size, void* d_ws,
                              size_t ws_size, hipStream_t stream) {
  const float* prompt = (const float*)d_in[0];
  const float* vis = (const float*)d_in[1];
  const float* dustbin = (const float*)d_in[2];
  float* out = (float*)d_out;  // p_obs [B*C] then total_mass [B]

  if (ws_size >= kVis8Bytes) {
    unsigned char* vis8 = (unsigned char*)d_ws;
    fused_kernel<<<kB, 1024, 0, stream>>>(prompt, vis, dustbin, vis8, out,
                                          out + (size_t)kB * kC);
  } else {
    float* ws = (float*)d_ws;
    float* sim = ws + kFbSimOff;
    float* gamma = ws + kFbGammaOff;
    float* partial = ws + kFbPartialOff;
    const long long rows = (long long)kB * kNP1;
    sim_kernel<<<(int)((rows + 3) / 4), 256, 0, stream>>>(prompt, vis,
                                                          dustbin, sim);
    sinkhorn_kernel<<<kB, 1024, 0, stream>>>(sim, gamma, out + (size_t)kB * kC);
    pobs_kernel<<<kB * kNSplit, 512, 0, stream>>>(vis, gamma, partial);
    reduce_kernel<<<(kB * kC + 255) / 256, 256, 0, stream>>>(partial, out);
  }
}

// Round 4
// 159.054 us; speedup vs baseline: 1.0369x; 1.0369x over previous
//
#include <hip/hip_runtime.h>
#include <math.h>

namespace {
constexpr int kB = 256;
constexpr int kN = 1024;
constexpr int kC = 512;
constexpr int kNP1 = kN + 1;  // 1025 (visual rows + dustbin)
constexpr float kEPS = 1e-6f;
constexpr float kPOW = 0.9523809523809523f;    // ALPHA/(ALPHA+REG) = 1/1.05
constexpr float kSCALE = 28.8539008177792681f; // 20 * log2(e)

// ---- fast-path ws layout (bytes) ----
constexpr size_t kVis8Bytes = (size_t)kB * kN * kC;  // 134,217,728
constexpr size_t kSimOffB = kVis8Bytes;
constexpr size_t kWsNeeded = kVis8Bytes + (size_t)kB * kNP1 * sizeof(float);

// ---- fallback ws layout (floats) ----
constexpr size_t kFbSimOff = 0;
constexpr size_t kFbGammaOff = (size_t)kB * kNP1;
constexpr size_t kFbPartialOff = kFbGammaOff + (size_t)kB * kN;
constexpr int kNSplit = 4;
constexpr int kRowsPerSplit = kN / kNSplit;  // 256

typedef float f32x2 __attribute__((ext_vector_type(2)));
typedef float f32x4 __attribute__((ext_vector_type(4)));
}  // namespace

// ===========================================================================
// K1: sims + fp8 copy. 4096 blocks x 256 threads; each wave owns 16
// consecutive rows of one batch (prompt fragment + its norm loaded ONCE).
// fp32 vis reads are nontemporal (read-once) so the cacheable vis8 writes
// stay LLC-resident for K2's read-back.
// ===========================================================================
__global__ __launch_bounds__(256) void sim_fp8_kernel(
    const float* __restrict__ prompt,       // [B, C]
    const float* __restrict__ vis,          // [B, N, C]
    const float* __restrict__ dustbin,      // [C]
    float* __restrict__ sim,                // [B, NP1]
    unsigned char* __restrict__ vis8) {     // [B, N, C] e4m3
  const int w = threadIdx.x >> 6;          // wave 0..3
  const int lane = threadIdx.x & 63;
  const int b = blockIdx.x >> 4;           // 16 blocks per batch
  const int chunk = blockIdx.x & 15;
  const int row0 = chunk * 64 + w * 16;    // first row (within batch)
  const int coff = lane * 8;               // lane owns channels [coff,coff+8)

  // prompt fragment + norm, once per wave
  const float* prow = prompt + (size_t)b * kC;
  const f32x4 pa = *reinterpret_cast<const f32x4*>(prow + coff);
  const f32x4 pb = *reinterpret_cast<const f32x4*>(prow + coff + 4);
  float psq = pa.x * pa.x + pa.y * pa.y + pa.z * pa.z + pa.w * pa.w +
              pb.x * pb.x + pb.y * pb.y + pb.z * pb.z + pb.w * pb.w;
#pragma unroll
  for (int s = 1; s < 64; s <<= 1) psq += __shfl_xor(psq, s);
  const float pn = fmaxf(sqrtf(psq), 1e-12f);

  const size_t base = ((size_t)b * kN + row0) * kC;
  const float* vptr = vis + base;
  unsigned char* v8ptr = vis8 + base;
  float* simw = sim + (size_t)b * kNP1 + row0;

#pragma unroll 2
  for (int r = 0; r < 16; ++r) {
    const float* vrow = vptr + (size_t)r * kC;
    const f32x4 va = __builtin_nontemporal_load(
        reinterpret_cast<const f32x4*>(vrow + coff));
    const f32x4 vb = __builtin_nontemporal_load(
        reinterpret_cast<const f32x4*>(vrow + coff + 4));

    float dot = va.x * pa.x + va.y * pa.y + va.z * pa.z + va.w * pa.w +
                vb.x * pb.x + vb.y * pb.y + vb.z * pb.z + vb.w * pb.w;
    float vsq = va.x * va.x + va.y * va.y + va.z * va.z + va.w * va.w +
                vb.x * vb.x + vb.y * vb.y + vb.z * vb.z + vb.w * vb.w;

    int pk0 = __builtin_amdgcn_cvt_pk_fp8_f32(va.x, va.y, 0, false);
    pk0 = __builtin_amdgcn_cvt_pk_fp8_f32(va.z, va.w, pk0, true);
    int pk1 = __builtin_amdgcn_cvt_pk_fp8_f32(vb.x, vb.y, 0, false);
    pk1 = __builtin_amdgcn_cvt_pk_fp8_f32(vb.z, vb.w, pk1, true);
    uint2 wv;
    wv.x = (unsigned)pk0;
    wv.y = (unsigned)pk1;
    *reinterpret_cast<uint2*>(v8ptr + (size_t)r * kC + coff) = wv;

#pragma unroll
    for (int s = 1; s < 64; s <<= 1) {
      dot += __shfl_xor(dot, s);
      vsq += __shfl_xor(vsq, s);
    }
    if (lane == 0)
      simw[r] = dot / (pn * fmaxf(sqrtf(vsq), 1e-12f));
  }

  // dustbin row: one wave per batch (last chunk, wave 3)
  if (chunk == 15 && w == 3) {
    const f32x4 da = *reinterpret_cast<const f32x4*>(dustbin + coff);
    const f32x4 db = *reinterpret_cast<const f32x4*>(dustbin + coff + 4);
    float dot = da.x * pa.x + da.y * pa.y + da.z * pa.z + da.w * pa.w +
                db.x * pb.x + db.y * pb.y + db.z * pb.z + db.w * pb.w;
    float vsq = da.x * da.x + da.y * da.y + da.z * da.z + da.w * da.w +
                db.x * db.x + db.y * db.y + db.z * db.z + db.w * db.w;
#pragma unroll
    for (int s = 1; s < 64; s <<= 1) {
      dot += __shfl_xor(dot, s);
      vsq += __shfl_xor(vsq, s);
    }
    if (lane == 0)
      sim[(size_t)b * kNP1 + kN] = dot / (pn * fmaxf(sqrtf(vsq), 1e-12f));
  }
}

// ===========================================================================
// K2: Sinkhorn + einsum + outputs. 512 blocks (batch x channel-half) x 1024.
// Sinkhorn (over all 1025 n) duplicated per half (cheap VALU); einsum covers
// 256 channels per block -> 2 blocks/CU-worth of TLP on the vis8 read-back.
// ===========================================================================
__global__ __launch_bounds__(1024) void sinkhorn_pobs_kernel(
    const float* __restrict__ sim,           // [B, NP1]
    const unsigned char* __restrict__ vis8,  // [B, N, C] e4m3
    float* __restrict__ p_obs,               // [B, C]
    float* __restrict__ mass_out) {          // [B]
  const int b = blockIdx.x >> 1;
  const int half = blockIdx.x & 1;
  const int t = threadIdx.x;
  const int w = t >> 6;
  const int lane = t & 63;

  __shared__ float red[16];
  __shared__ float gs[kN];
  __shared__ f32x4 pacc[16][64];  // 16 KB einsum partials

  const float* simb = sim + (size_t)b * kNP1;
  const float K0 = exp2f((simb[t] - 1.0f) * kSCALE);
  const float Kd = (t == 0) ? exp2f((simb[kN] - 1.0f) * kSCALE) : 0.0f;
  float v0 = 1.0f, vd = 1.0f, u = 1.0f;

#pragma unroll
  for (int it = 0; it < 3; ++it) {
    float partial = K0 * v0 + Kd * vd;
#pragma unroll
    for (int s = 1; s < 64; s <<= 1) partial += __shfl_xor(partial, s);
    if (lane == 0) red[w] = partial;
    __syncthreads();
    float Kv = 0.f;
#pragma unroll
    for (int w2 = 0; w2 < 16; ++w2) Kv += red[w2];
    __syncthreads();
    u = exp2f(-kPOW * log2f(Kv + kEPS));
    v0 = exp2f(-kPOW * log2f(u * K0 + kEPS));
    vd = exp2f(-kPOW * log2f(u * Kd + kEPS));
  }

  const float g = u * K0 * v0;  // gamma for n = t (< N always)
  gs[t] = g;

  float pm = g;
#pragma unroll
  for (int s = 1; s < 64; s <<= 1) pm += __shfl_xor(pm, s);
  if (lane == 0) red[w] = pm;
  __syncthreads();  // publishes gs + red
  if (t == 0 && half == 0) {
    float m = 0.f;
#pragma unroll
    for (int w2 = 0; w2 < 16; ++w2) m += red[w2];
    mass_out[b] = m;
  }

  // einsum: channels [half*256 + lane*4, +4); wave w handles n = w + 16k
  const int cbase = half * 256 + lane * 4;
  f32x4 acc = {0.f, 0.f, 0.f, 0.f};
  const unsigned char* v8 = vis8 + (size_t)b * kN * kC + cbase;
#pragma unroll 8
  for (int k = 0; k < 64; ++k) {
    const int n = w + (k << 4);
    const float gn = gs[n];
    const unsigned wd = *reinterpret_cast<const unsigned*>(v8 + (size_t)n * kC);
    const f32x2 f01 = __builtin_amdgcn_cvt_pk_f32_fp8(wd, false);
    const f32x2 f23 = __builtin_amdgcn_cvt_pk_f32_fp8(wd, true);
    acc.x += gn * f01.x;
    acc.y += gn * f01.y;
    acc.z += gn * f23.x;
    acc.w += gn * f23.y;
  }
  pacc[w][lane] = acc;
  __syncthreads();
  if (t < 256) {
    // channel offset within half: c = t ; component t&3 of lane t>>2
    float s = 0.f;
#pragma unroll
    for (int ss = 0; ss < 16; ++ss) {
      const f32x4 p = pacc[ss][t >> 2];
      s += (t & 3) == 0 ? p.x : ((t & 3) == 1 ? p.y : ((t & 3) == 2 ? p.z : p.w));
    }
    p_obs[(size_t)b * kC + half * 256 + t] = s;
  }
}

// ===========================================================================
// FALLBACK (fp32 two-pass, round-1 proven; used only if ws < 134.2 MB)
// ===========================================================================
__global__ __launch_bounds__(256) void sim_kernel(
    const float* __restrict__ prompt, const float* __restrict__ vis,
    const float* __restrict__ dustbin, float* __restrict__ sim) {
  const int wid = threadIdx.x >> 6;
  const int lane = threadIdx.x & 63;
  const long long row = (long long)blockIdx.x * 4 + wid;
  if (row >= (long long)kB * kNP1) return;
  const int b = (int)(row / kNP1);
  const int n = (int)(row % kNP1);
  const float* vrow = (n < kN) ? (vis + ((size_t)b * kN + n) * kC) : dustbin;
  const float* prow = prompt + (size_t)b * kC;
  float dot = 0.f, vsq = 0.f, psq = 0.f;
#pragma unroll
  for (int h = 0; h < 2; ++h) {
    const int off = h * 256 + lane * 4;
    const float4 v4 = *reinterpret_cast<const float4*>(vrow + off);
    const float4 p4 = *reinterpret_cast<const float4*>(prow + off);
    dot += v4.x * p4.x + v4.y * p4.y + v4.z * p4.z + v4.w * p4.w;
    vsq += v4.x * v4.x + v4.y * v4.y + v4.z * v4.z + v4.w * v4.w;
    psq += p4.x * p4.x + p4.y * p4.y + p4.z * p4.z + p4.w * p4.w;
  }
#pragma unroll
  for (int s = 1; s < 64; s <<= 1) {
    dot += __shfl_xor(dot, s);
    vsq += __shfl_xor(vsq, s);
    psq += __shfl_xor(psq, s);
  }
  if (lane == 0) {
    const float pn = fmaxf(sqrtf(psq), 1e-12f);
    const float vn = fmaxf(sqrtf(vsq), 1e-12f);
    sim[row] = dot / (pn * vn);
  }
}

__global__ __launch_bounds__(1024) void sinkhorn_kernel(
    const float* __restrict__ sim, float* __restrict__ gamma,
    float* __restrict__ mass_out) {
  const int b = blockIdx.x;
  const int t = threadIdx.x;
  __shared__ float red[16];
  const float* simb = sim + (size_t)b * kNP1;
  const float K0 = exp2f((simb[t] - 1.0f) * kSCALE);
  const float K1 = (t == 0) ? exp2f((simb[kN] - 1.0f) * kSCALE) : 0.0f;
  float v0 = 1.0f, v1 = 1.0f, u = 1.0f;
  for (int it = 0; it < 3; ++it) {
    float partial = K0 * v0 + K1 * v1;
#pragma unroll
    for (int s = 1; s < 64; s <<= 1) partial += __shfl_xor(partial, s);
    if ((t & 63) == 0) red[t >> 6] = partial;
    __syncthreads();
    float Kv = 0.f;
#pragma unroll
    for (int w = 0; w < 16; ++w) Kv += red[w];
    __syncthreads();
    u = exp2f(-kPOW * log2f(Kv + kEPS));
    v0 = exp2f(-kPOW * log2f(u * K0 + kEPS));
    v1 = exp2f(-kPOW * log2f(u * K1 + kEPS));
  }
  const float g0 = u * K0 * v0;
  gamma[(size_t)b * kN + t] = g0;
  float partial = g0;
#pragma unroll
  for (int s = 1; s < 64; s <<= 1) partial += __shfl_xor(partial, s);
  if ((t & 63) == 0) red[t >> 6] = partial;
  __syncthreads();
  if (t == 0) {
    float m = 0.f;
#pragma unroll
    for (int w = 0; w < 16; ++w) m += red[w];
    mass_out[b] = m;
  }
}

__global__ __launch_bounds__(512) void pobs_kernel(
    const float* __restrict__ vis, const float* __restrict__ gamma,
    float* __restrict__ partial) {
  const int b = blockIdx.x / kNSplit;
  const int s = blockIdx.x % kNSplit;
  const int c = threadIdx.x;
  __shared__ float gsm[kRowsPerSplit];
  const float* g = gamma + (size_t)b * kN + (size_t)s * kRowsPerSplit;
  for (int i = threadIdx.x; i < kRowsPerSplit; i += 512) gsm[i] = g[i];
  __syncthreads();
  const float* vbase = vis + ((size_t)b * kN + (size_t)s * kRowsPerSplit) * kC;
  float acc = 0.f;
#pragma unroll 8
  for (int n = 0; n < kRowsPerSplit; ++n)
    acc += gsm[n] * vbase[(size_t)n * kC + c];
  partial[(size_t)blockIdx.x * kC + c] = acc;
}

__global__ __launch_bounds__(256) void reduce_kernel(
    const float* __restrict__ partial, float* __restrict__ p_obs) {
  const int i = blockIdx.x * 256 + threadIdx.x;
  if (i >= kB * kC) return;
  const int b = i / kC;
  const int c = i % kC;
  float s = 0.f;
#pragma unroll
  for (int k = 0; k < kNSplit; ++k)
    s += partial[((size_t)(b * kNSplit + k)) * kC + c];
  p_obs[i] = s;
}

// ===========================================================================

extern "C" void kernel_launch(void* const* d_in, const int* in_sizes, int n_in,
                              void* d_out, int out_size, void* d_ws,
                              size_t ws_size, hipStream_t stream) {
  const float* prompt = (const float*)d_in[0];
  const float* vis = (const float*)d_in[1];
  const float* dustbin = (const float*)d_in[2];
  float* out = (float*)d_out;  // p_obs [B*C] then total_mass [B]

  if (ws_size >= kWsNeeded) {
    unsigned char* vis8 = (unsigned char*)d_ws;
    float* sim = (float*)((unsigned char*)d_ws + kSimOffB);
    sim_fp8_kernel<<<kB * 16, 256, 0, stream>>>(prompt, vis, dustbin, sim,
                                                vis8);
    sinkhorn_pobs_kernel<<<kB * 2, 1024, 0, stream>>>(
        sim, vis8, out, out + (size_t)kB * kC);
  } else {
    float* ws = (float*)d_ws;
    float* sim = ws + kFbSimOff;
    float* gamma = ws + kFbGammaOff;
    float* partial = ws + kFbPartialOff;
    const long long rows = (long long)kB * kNP1;
    sim_kernel<<<(int)((rows + 3) / 4), 256, 0, stream>>>(prompt, vis,
                                                          dustbin, sim);
    sinkhorn_kernel<<<kB, 1024, 0, stream>>>(sim, gamma, out + (size_t)kB * kC);
    pobs_kernel<<<kB * kNSplit, 512, 0, stream>>>(vis, gamma, partial);
    reduce_kernel<<<(kB * kC + 255) / 256, 256, 0, stream>>>(partial, out);
  }
}